// Round 10
// baseline (307.302 us; speedup 1.0000x reference)
//
#include <hip/hip_runtime.h>
#include <stdint.h>

typedef unsigned long long u64;

#define PTOT 1024
#define CF   512
#define NBOX 9216
#define NPAD 9280          // 145 words of 64
#define NW   144
#define TOPK 300
#define RCH  19            // rank b-chunks of 8 words: 19*8=152 >= 145

__device__ __forceinline__ uint32_t score_key(float s) {
  uint32_t b = __float_as_uint(s);
  uint32_t o = (b & 0x80000000u) ? ~b : (b | 0x80000000u);
  return ~o;  // ascending in key == descending in score
}

#define FMA16() do { \
  acc[0][0] = fmaf(bv.x, av.x, acc[0][0]); \
  acc[0][1] = fmaf(bv.x, av.y, acc[0][1]); \
  acc[0][2] = fmaf(bv.x, av.z, acc[0][2]); \
  acc[0][3] = fmaf(bv.x, av.w, acc[0][3]); \
  acc[1][0] = fmaf(bv.y, av.x, acc[1][0]); \
  acc[1][1] = fmaf(bv.y, av.y, acc[1][1]); \
  acc[1][2] = fmaf(bv.y, av.z, acc[1][2]); \
  acc[1][3] = fmaf(bv.y, av.w, acc[1][3]); \
  acc[2][0] = fmaf(bv.z, av.x, acc[2][0]); \
  acc[2][1] = fmaf(bv.z, av.y, acc[2][1]); \
  acc[2][2] = fmaf(bv.z, av.z, acc[2][2]); \
  acc[2][3] = fmaf(bv.z, av.w, acc[2][3]); \
  acc[3][0] = fmaf(bv.w, av.x, acc[3][0]); \
  acc[3][1] = fmaf(bv.w, av.y, acc[3][1]); \
  acc[3][2] = fmaf(bv.w, av.z, acc[3][2]); \
  acc[3][3] = fmaf(bv.w, av.w, acc[3][3]); \
} while (0)

// ---------------- weight transpose: wT[k][co] = w[co][k] ----------------
__global__ __launch_bounds__(256) void k_wt(const float* __restrict__ w_rpn,
                                            const float* __restrict__ w_bb,
                                            float* __restrict__ wT,
                                            float* __restrict__ wT1) {
  __shared__ float T[32][33];
  int bx = blockIdx.x;
  const float* src; float* dst; int K, kb;
  if (bx < 144) { src = w_rpn; dst = wT; K = 4608; kb = bx * 32; }
  else          { src = w_bb;  dst = wT1; K = 768; kb = (bx - 144) * 32; }
  const int cob = blockIdx.y * 32;
  const int tx = threadIdx.x & 31, ty = threadIdx.x >> 5;
#pragma unroll
  for (int r = 0; r < 32; r += 8)
    T[ty + r][tx] = src[(cob + ty + r) * K + kb + tx];
  __syncthreads();
#pragma unroll
  for (int r = 0; r < 32; r += 8)
    dst[(kb + ty + r) * 512 + cob + tx] = T[tx][ty + r];
}

// ---------------- conv1: 16x16 stride16 patchify, split-K over c (z=0..2) ----------------
__global__ __launch_bounds__(256) void k_conv1(const float* __restrict__ img,
                                               const float* __restrict__ wT1,
                                               float* __restrict__ featP) {
  __shared__ __align__(16) float As[32][72];
  __shared__ __align__(16) float Bs[32][64];
  const int t = threadIdx.x;
  const int pbase = blockIdx.x * 64;
  const int cobase = blockIdx.y * 64;
  const int z = blockIdx.z;
  const int pg = t & 15, cg = t >> 4;
  const int pp0 = pg * 4, cc0 = cg * 4;
  const int py0 = pbase >> 5;
  float acc[4][4] = {};
  for (int kb = 0; kb < 256; kb += 32) {
    const int ky0 = kb >> 4;
#pragma unroll
    for (int l0 = 0; l0 < 2048; l0 += 256) {
      int l = l0 + t;
      int seg = l >> 9, off = l & 511;
      int py_off = seg >> 1, ky_off = seg & 1;
      int row = (py0 + py_off) * 16 + ky0 + ky_off;
      float v = img[(z * 512 + row) * 512 + off];
      As[ky_off * 16 + (off & 15)][py_off * 32 + (off >> 4)] = v;
    }
#pragma unroll
    for (int it = 0; it < 2; ++it) {
      int idx4 = it * 256 + t;
      int k = idx4 >> 4, co4 = (idx4 & 15) << 2;
      *(float4*)&Bs[k][co4] =
          *(const float4*)&wT1[(z * 256 + kb + k) * 512 + cobase + co4];
    }
    __syncthreads();
#pragma unroll
    for (int kk = 0; kk < 32; ++kk) {
      float4 av = *(const float4*)&As[kk][pp0];
      float4 bv = *(const float4*)&Bs[kk][cc0];
      FMA16();
    }
    __syncthreads();
  }
#pragma unroll
  for (int i = 0; i < 4; ++i) {
    float* o = &featP[((size_t)z * CF + cobase + cc0 + i) * PTOT + pbase + pp0];
    *(float4*)o = make_float4(acc[i][0], acc[i][1], acc[i][2], acc[i][3]);
  }
}

// ---------------- reduce1: feat = relu(sum_z featP + bias) ----------------
__global__ __launch_bounds__(256) void k_reduce1(const float* __restrict__ featP,
                                                 const float* __restrict__ bias,
                                                 float* __restrict__ feat) {
  int idx4 = blockIdx.x * 256 + threadIdx.x;
  int co = idx4 >> 8;
  const float4* f = (const float4*)featP;
  float4 a = f[idx4];
  float4 b = f[idx4 + 131072];
  float4 c = f[idx4 + 262144];
  float bb = bias[co];
  float4 o;
  o.x = fmaxf(a.x + b.x + c.x + bb, 0.f);
  o.y = fmaxf(a.y + b.y + c.y + bb, 0.f);
  o.z = fmaxf(a.z + b.z + c.z + bb, 0.f);
  o.w = fmaxf(a.w + b.w + c.w + bb, 0.f);
  ((float4*)feat)[idx4] = o;
}

// ---------------- conv2 v3: 3x3 SAME, 128px x 64co tile, split-K Z ----------------
__global__ __launch_bounds__(256) void k_conv2(const float* __restrict__ feat,
                                               const float* __restrict__ wT,
                                               float* __restrict__ hidP,
                                               int ciPerZ) {
  __shared__ __align__(16) float As[8][6][44];
  __shared__ __align__(16) float Bs[72 * 64];
  const int t = threadIdx.x;
  const int pyb = blockIdx.x * 4;
  const int cob = blockIdx.y * 64;
  const int z = blockIdx.z;
  const int cib = z * ciPerZ;
  const int pg = t & 15, cg = t >> 4;
  const int prow = pg >> 2, px0 = (pg & 3) * 8;
  const int co0 = cg * 4;
  float acc[4][8] = {};
  for (int cc = 0; cc < ciPerZ; cc += 8) {
    {
      int idx4 = t;
#pragma unroll
      for (int it = 0; it < 2; ++it, idx4 += 256) {
        if (idx4 < 480) {
          int ci = idx4 / 60;
          int rem = idx4 - ci * 60;
          int row = rem / 10;
          int col4 = (rem - row * 10) << 2;
          int x = col4 - 4;
          int gy = pyb + row - 1;
          float4 v = make_float4(0.f, 0.f, 0.f, 0.f);
          if (x >= 0 && x < 32 && gy >= 0 && gy < 32)
            v = *(const float4*)&feat[(cib + cc + ci) * PTOT + gy * 32 + x];
          *(float4*)&As[ci][row][col4] = v;
        }
      }
    }
    {
      const int kg0 = (cib + cc) * 9;
      int idx4 = t;
#pragma unroll
      for (int it = 0; it < 5; ++it, idx4 += 256) {
        if (idx4 < 1152) {
          int k = idx4 >> 4;
          int co4 = (idx4 & 15) << 2;
          *(float4*)&Bs[k * 64 + co4] =
              *(const float4*)&wT[(kg0 + k) * 512 + cob + co4];
        }
      }
    }
    __syncthreads();
#pragma unroll 1
    for (int ci = 0; ci < 8; ++ci) {
#pragma unroll
      for (int dy = 0; dy < 3; ++dy) {
        const float* Ar = &As[ci][prow + dy][px0];
        float rw[16];
        *(float4*)&rw[0]  = *(const float4*)&Ar[0];
        *(float4*)&rw[4]  = *(const float4*)&Ar[4];
        *(float4*)&rw[8]  = *(const float4*)&Ar[8];
        *(float4*)&rw[12] = *(const float4*)&Ar[12];
#pragma unroll
        for (int dx = 0; dx < 3; ++dx) {
          const float* Bp = &Bs[(ci * 9 + dy * 3 + dx) * 64 + co0];
          float4 b0 = *(const float4*)&Bp[0];
          float bm[4] = {b0.x, b0.y, b0.z, b0.w};
#pragma unroll
          for (int m = 0; m < 4; ++m)
#pragma unroll
            for (int j = 0; j < 8; ++j)
              acc[m][j] = fmaf(rw[3 + dx + j], bm[m], acc[m][j]);
        }
      }
    }
    __syncthreads();
  }
  const int prowg = pyb + prow;
#pragma unroll
  for (int m = 0; m < 4; ++m) {
    int co = cob + co0 + m;
    float* o = &hidP[((size_t)z * CF + co) * PTOT + prowg * 32 + px0];
    *(float4*)&o[0] = make_float4(acc[m][0], acc[m][1], acc[m][2], acc[m][3]);
    *(float4*)&o[4] = make_float4(acc[m][4], acc[m][5], acc[m][6], acc[m][7]);
  }
}

// ---------------- reduce2 v2: 32x32 tiles, 512 blocks (was 128 -> 0.5/CU) ----------------
__global__ __launch_bounds__(256) void k_reduce2(const float* __restrict__ hidP,
                                                 const float* __restrict__ bias,
                                                 float* __restrict__ hid_t, int Z) {
  __shared__ float T[32][33];
  const int co0 = blockIdx.x * 32, p0 = blockIdx.y * 32;
  const int t = threadIdx.x;
  {
    int co = t >> 3, p4 = (t & 7) << 2;
    float4 s = make_float4(0.f, 0.f, 0.f, 0.f);
    for (int zz = 0; zz < Z; ++zz) {
      float4 v = *(const float4*)&hidP[((size_t)zz * CF + co0 + co) * PTOT + p0 + p4];
      s.x += v.x; s.y += v.y; s.z += v.z; s.w += v.w;
    }
    float b = bias[co0 + co];
    T[co][p4 + 0] = fmaxf(s.x + b, 0.f);
    T[co][p4 + 1] = fmaxf(s.y + b, 0.f);
    T[co][p4 + 2] = fmaxf(s.z + b, 0.f);
    T[co][p4 + 3] = fmaxf(s.w + b, 0.f);
  }
  __syncthreads();
  {
    int p = t >> 3, co4 = (t & 7) << 2;
    float4 o = make_float4(T[co4][p], T[co4 + 1][p], T[co4 + 2][p], T[co4 + 3][p]);
    *(float4*)&hid_t[(size_t)(p0 + p) * CF + co0 + co4] = o;
  }
}

// ---------------- heads: one wave per pixel; emits score KEYS + deltas ----------------
__global__ __launch_bounds__(256) void k_heads(const float* __restrict__ hid_t,
                                               const float* __restrict__ wcls,
                                               const float* __restrict__ bcls,
                                               const float* __restrict__ wbox,
                                               const float* __restrict__ bbox,
                                               uint32_t* __restrict__ key32,
                                               float* __restrict__ deltas) {
  const int t = threadIdx.x;
  if (blockIdx.x == 256) {
    if (t < 64) key32[NBOX + t] = 0xFFFFFFFFu;
    return;
  }
  const int lane = t & 63, w = t >> 6;
  const int p = blockIdx.x * 4 + w;
  const float* hp = &hid_t[(size_t)p * CF + lane * 8];
  float4 h0 = *(const float4*)hp;
  float4 h1 = *(const float4*)(hp + 4);
#pragma unroll 1
  for (int ch = 0; ch < 45; ++ch) {
    const float* wp = (ch < 9) ? &wcls[(9 + ch) * CF] : &wbox[(ch - 9) * CF];
    float4 w0 = *(const float4*)(wp + lane * 8);
    float4 w1 = *(const float4*)(wp + lane * 8 + 4);
    float s = h0.x * w0.x + h0.y * w0.y + h0.z * w0.z + h0.w * w0.w +
              h1.x * w1.x + h1.y * w1.y + h1.z * w1.z + h1.w * w1.w;
#pragma unroll
    for (int off = 32; off >= 1; off >>= 1) s += __shfl_xor(s, off, 64);
    if (lane == 0) {
      if (ch < 9) key32[p * 9 + ch] = score_key(s + bcls[9 + ch]);
      else        deltas[p * 36 + (ch - 9)] = s + bbox[ch - 9];
    }
  }
}

// ---------------- rank sort stage 1: partial ranks via SGPR-broadcast all-pairs ----------------
__global__ __launch_bounds__(256) void k_rank(const uint32_t* __restrict__ key32,
                                              uint32_t* __restrict__ P) {
  const int t = threadIdx.x;
  const int lane = t & 63, w = t >> 6;
  const int a = blockIdx.x * 4 + w;
  if (a >= 145) return;
  const int by = blockIdx.y;
  const int ig = a * 64 + lane;
  const uint32_t ka = key32[ig];
  uint32_t cnt = 0;
#pragma unroll 1
  for (int w2 = 0; w2 < 8; ++w2) {
    int word = by * 8 + w2;
    if (word >= 145) break;
    const uint32_t* bk = &key32[word * 64];
    const int jbase = word * 64;
#pragma unroll
    for (int s = 0; s < 64; ++s) {
      uint32_t kb = bk[s];                         // uniform -> s_load
      int j = jbase + s;
      cnt += (uint32_t)((kb < ka) || (kb == ka && j < ig));
    }
  }
  P[(size_t)by * NPAD + ig] = cnt;
}

// ---------------- rank sort stage 2: sum partials + decode + scatter ----------------
__global__ __launch_bounds__(256) void k_rfin(const uint32_t* __restrict__ P,
                                              const float* __restrict__ anchors,
                                              const float* __restrict__ deltas,
                                              float4* __restrict__ boxesS) {
  int i = blockIdx.x * 256 + threadIdx.x;
  if (i >= NBOX) return;
  uint32_t rank = 0;
#pragma unroll
  for (int c = 0; c < RCH; ++c) rank += P[(size_t)c * NPAD + i];
  float4 a = ((const float4*)anchors)[i];
  float4 d = ((const float4*)deltas)[i];
  float wa = a.z - a.x, ha = a.w - a.y;
  float cxa = a.x + 0.5f * wa, cya = a.y + 0.5f * ha;
  float dw = fminf(fmaxf(d.z, -4.f), 4.f);
  float dh = fminf(fmaxf(d.w, -4.f), 4.f);
  float cx = cxa + d.x * wa, cy = cya + d.y * ha;
  float ww = wa * expf(dw), hh = ha * expf(dh);
  float x1 = fmaxf(cx - 0.5f * ww, 0.f);
  float y1 = fmaxf(cy - 0.5f * hh, 0.f);
  float x2 = fminf(cx + 0.5f * ww, 511.f);
  float y2 = fminf(cy + 0.5f * hh, 511.f);
  boxesS[rank] = make_float4(x1, y1, x2, y2);
}

// ---------------- IOU bitmask v5: uniform word-pair enumeration, sign-safe compare ----------------
__global__ __launch_bounds__(256) void k_iou(const float4* __restrict__ boxesS,
                                             u64* __restrict__ mask) {
  __shared__ float4 cb[4][64];
  __shared__ float ca[4][64];
  const int t = threadIdx.x;
  const int lane = t & 63, w = t >> 6;
  const int u = blockIdx.x;                        // 0..144
  const int v = blockIdx.y * 4 + w + 1;            // 1..72
  int y = u + v; if (y >= 145) y -= 145;
  const int a_ = min(u, y), b_ = max(u, y);
  const int iw = a_, wj = b_ - 1;                  // iw <= wj in [0,144)

  {
    float4 c = boxesS[wj * 64 + lane];
    cb[w][lane] = c;
    ca[w][lane] = (c.z - c.x) * (c.w - c.y);
  }
  __syncthreads();

  const int i = iw * 64 + lane;
  float4 a = boxesS[i];
  float areaA = (a.z - a.x) * (a.w - a.y);
  u64 bits = 0;
#pragma unroll 4
  for (int jj = 0; jj < 64; ++jj) {
    int j = wj * 64 + jj;
    float4 c = cb[w][jj];
    float iw_ = fmaxf(fminf(a.z, c.z) - fmaxf(a.x, c.x), 0.f);
    float ih_ = fmaxf(fminf(a.w, c.w) - fmaxf(a.y, c.y), 0.f);
    float inter = iw_ * ih_;
    float uni = areaA + ca[w][jj] - inter + 1e-9f;
    float thr = 0.7f * uni;
    bool pos = uni > 0.f;
    bool sup = pos && (inter > thr);
    if (pos && (fabsf(inter - thr) <= thr * 1e-5f))  // rare: exact IEEE path
      sup = (inter / uni) > 0.7f;
    bits |= ((u64)(sup && (j > i))) << jj;
  }
  mask[(size_t)i * NW + wj] = bits;
}

// ---------------- NMS scan v5: sparse shuffle chain, barrier-free main loop ----------------
// Diagonal words live in registers (lane r holds row r's word). Chain iterates
// only un-suppressed candidates via ffs(~R); row word fetched by __shfl — no
// LDS round-trip, no Dbuf, no __syncthreads in the span loop (single wave).
__global__ __launch_bounds__(64) void k_scan(const u64* __restrict__ mask,
                                             const float4* __restrict__ boxesS,
                                             float* __restrict__ out) {
  __shared__ u64 keepArr[NW];
  __shared__ int pf[NW + 2];
  __shared__ int outIdx[TOPK];
  const int lane = threadIdx.x;

  u64 r0 = 0, r1 = 0, r2 = 0;
  int keptCount = 0;
  int stopSpan = NW - 1;

  u64 dcur = mask[(size_t)lane * NW];              // span-0 diagonal words

  for (int wb = 0; wb < NW; ++wb) {
    u64 v = (wb < 64) ? r0 : ((wb < 128) ? r1 : r2);
    u64 R = __shfl(v, wb & 63, 64);

    u64 dnext = 0;                                 // prefetch next diagonal
    if (wb + 1 < NW)
      dnext = mask[(size_t)((wb + 1) * 64 + lane) * NW + (wb + 1)];

    u64 keepmask = 0;
    u64 notR = ~R;
    while (notR) {                                 // sparse greedy chain
      int rl = __ffsll((long long)notR) - 1;
      keepmask |= 1ull << rl;
      u64 drl = __shfl(dcur, rl, 64);              // row rl's same-span word
      R |= drl;
      u64 above = (rl >= 63) ? 0ull : (~0ull << (rl + 1));
      notR = ~R & above;
    }

    if (keepmask) {                                // OR kept rows, 8 in flight
      u64 km = keepmask;
      while (km) {
        int first = wb * 64 + __ffsll((long long)km) - 1;
        int idx[8];
#pragma unroll
        for (int s = 0; s < 8; ++s) {
          if (km) { idx[s] = wb * 64 + __ffsll((long long)km) - 1; km &= km - 1; }
          else    { idx[s] = first; }
        }
        u64 A[8], B[8], C[8];
#pragma unroll
        for (int s = 0; s < 8; ++s) {
          const u64* q = mask + (size_t)idx[s] * NW;
          A[s] = q[lane];
          B[s] = q[lane + 64];
          C[s] = (lane < 16) ? q[lane + 128] : 0ull;
        }
#pragma unroll
        for (int s = 0; s < 8; ++s) { r0 |= A[s]; r1 |= B[s]; r2 |= C[s]; }
      }
      keptCount += __popcll(keepmask);
    }
    if (lane == 0) keepArr[wb] = keepmask;
    dcur = dnext;
    if (keptCount >= TOPK) { stopSpan = wb; break; }
  }

  __syncthreads();
  if (lane == 0) {
    int acc = 0;
    for (int s = 0; s <= stopSpan; ++s) { pf[s] = acc; acc += __popcll(keepArr[s]); }
    pf[stopSpan + 1] = acc;
  }
  __syncthreads();
  const int keptTotal = pf[stopSpan + 1];

  for (int s = lane; s <= stopSpan; s += 64) {
    u64 km = keepArr[s];
    int slot = pf[s];
    while (km && slot < TOPK) {
      int rl = __ffsll((long long)km) - 1; km &= km - 1;
      outIdx[slot++] = s * 64 + rl;
    }
  }
  if (keptTotal < TOPK) {
    for (int s = lane; s <= stopSpan; s += 64) {
      u64 rm = ~keepArr[s];
      int slot = keptTotal + s * 64 - pf[s];
      while (rm && slot < TOPK) {
        int rl = __ffsll((long long)rm) - 1; rm &= rm - 1;
        outIdx[slot++] = s * 64 + rl;
      }
    }
  }
  __syncthreads();
#pragma unroll
  for (int k0 = 0; k0 < TOPK + 63; k0 += 64) {
    int k = k0 + lane;
    if (k < TOPK) {
      float4 bx = boxesS[outIdx[k]];
      out[k * 4 + 0] = bx.x;
      out[k * 4 + 1] = bx.y;
      out[k * 4 + 2] = bx.z;
      out[k * 4 + 3] = bx.w;
    }
  }
}

extern "C" void kernel_launch(void* const* d_in, const int* in_sizes, int n_in,
                              void* d_out, int out_size, void* d_ws, size_t ws_size,
                              hipStream_t stream) {
  const float* img   = (const float*)d_in[0];
  const float* anch  = (const float*)d_in[1];
  const float* w_bb  = (const float*)d_in[2];
  const float* b_bb  = (const float*)d_in[3];
  const float* w_rpn = (const float*)d_in[4];
  const float* b_rpn = (const float*)d_in[5];
  const float* w_cls = (const float*)d_in[6];
  const float* b_cls = (const float*)d_in[7];
  const float* w_box = (const float*)d_in[8];
  const float* b_box = (const float*)d_in[9];

  char* ws = (char*)d_ws;
  int Z = 16;
  if (ws_size < 22806528ull + 16ull * 2097152ull) Z = 8;
  if (ws_size < 22806528ull + 8ull * 2097152ull)  Z = 4;
  if (ws_size < 22806528ull + 4ull * 2097152ull)  Z = 2;
  if (ws_size < 22806528ull + 2ull * 2097152ull)  Z = 1;

  float* wT    = (float*)(ws);                      // 9 MB
  float* wT1   = (float*)(ws + 9437184);            // 1.5 MB
  float* featP = (float*)(ws + 11010048);           // 6 MB
  float* feat  = (float*)(ws + 17301504);           // 2 MB
  float* hidP  = (float*)(ws + 19398656);           // Z * 2 MB
  char*  hte   = ws + 19398656 + (size_t)Z * 2097152;
  float* hid_t = (float*)hte;                       // 2 MB
  char*  tail  = hte + 2097152;
  float*    deltas = (float*)(tail);                // 144 KB
  uint32_t* key32  = (uint32_t*)(tail + 0x28000);   // 37 KB
  float4*   boxesS = (float4*)(tail + 0x38000);     // 144 KB
  // Overlays of the dead featP/feat/hidP region:
  uint32_t* P      = (uint32_t*)(ws + 11010048);    // 705 KB (after heads)
  u64*      mask   = (u64*)(ws + 11010048);         // 10.6 MB (after k_rfin)
  float*    out    = (float*)d_out;

  hipLaunchKernelGGL(k_wt, dim3(168, 16), dim3(256), 0, stream, w_rpn, w_bb, wT, wT1);
  hipLaunchKernelGGL(k_conv1, dim3(16, 8, 3), dim3(256), 0, stream, img, wT1, featP);
  hipLaunchKernelGGL(k_reduce1, dim3(512), dim3(256), 0, stream, featP, b_bb, feat);
  hipLaunchKernelGGL(k_conv2, dim3(8, 8, Z), dim3(256), 0, stream, feat, wT, hidP, 512 / Z);
  hipLaunchKernelGGL(k_reduce2, dim3(16, 32), dim3(256), 0, stream, hidP, b_rpn, hid_t, Z);
  hipLaunchKernelGGL(k_heads, dim3(257), dim3(256), 0, stream, hid_t, w_cls, b_cls, w_box, b_box, key32, deltas);
  hipLaunchKernelGGL(k_rank, dim3(37, RCH), dim3(256), 0, stream, key32, P);
  hipLaunchKernelGGL(k_rfin, dim3(37), dim3(256), 0, stream, P, anch, deltas, boxesS);
  hipLaunchKernelGGL(k_iou, dim3(145, 18), dim3(256), 0, stream, boxesS, mask);
  hipLaunchKernelGGL(k_scan, dim3(1), dim3(64), 0, stream, mask, boxesS, out);
}

// Round 11
// 304.972 us; speedup vs baseline: 1.0076x; 1.0076x over previous
//
#include <hip/hip_runtime.h>
#include <stdint.h>

typedef unsigned long long u64;

#define PTOT 1024
#define CF   512
#define NBOX 9216
#define NPAD 9280          // 145 words of 64
#define NW   144
#define TOPK 300
#define RCH  19            // rank b-chunks of 8 words: 19*8=152 >= 145

__device__ __forceinline__ uint32_t score_key(float s) {
  uint32_t b = __float_as_uint(s);
  uint32_t o = (b & 0x80000000u) ? ~b : (b | 0x80000000u);
  return ~o;  // ascending in key == descending in score
}

#define FMA16() do { \
  acc[0][0] = fmaf(bv.x, av.x, acc[0][0]); \
  acc[0][1] = fmaf(bv.x, av.y, acc[0][1]); \
  acc[0][2] = fmaf(bv.x, av.z, acc[0][2]); \
  acc[0][3] = fmaf(bv.x, av.w, acc[0][3]); \
  acc[1][0] = fmaf(bv.y, av.x, acc[1][0]); \
  acc[1][1] = fmaf(bv.y, av.y, acc[1][1]); \
  acc[1][2] = fmaf(bv.y, av.z, acc[1][2]); \
  acc[1][3] = fmaf(bv.y, av.w, acc[1][3]); \
  acc[2][0] = fmaf(bv.z, av.x, acc[2][0]); \
  acc[2][1] = fmaf(bv.z, av.y, acc[2][1]); \
  acc[2][2] = fmaf(bv.z, av.z, acc[2][2]); \
  acc[2][3] = fmaf(bv.z, av.w, acc[2][3]); \
  acc[3][0] = fmaf(bv.w, av.x, acc[3][0]); \
  acc[3][1] = fmaf(bv.w, av.y, acc[3][1]); \
  acc[3][2] = fmaf(bv.w, av.z, acc[3][2]); \
  acc[3][3] = fmaf(bv.w, av.w, acc[3][3]); \
} while (0)

// ---------------- k_front: fused [w_rpn transpose] + [conv1] ----------------
// bid < 2304: transpose one 32x32 tile of w_rpn into wT[k][co].
// bid >= 2304: conv1 patchify block; reads w_bb DIRECTLY (in-LDS transpose,
// co=lane mapping -> conflict-free scalar LDS writes), so no wT1 dependency.
__global__ __launch_bounds__(256) void k_front(const float* __restrict__ w_rpn,
                                               const float* __restrict__ w_bb,
                                               const float* __restrict__ img,
                                               float* __restrict__ wT,
                                               float* __restrict__ featP) {
  __shared__ __align__(16) float As[32][72];
  __shared__ __align__(16) float Bs[32][64];
  __shared__ float Twt[32][33];
  const int bid = blockIdx.x;
  const int t = threadIdx.x;

  if (bid < 2304) {                                // ---- w_rpn transpose part
    const int kb = (bid >> 4) * 32;
    const int cob = (bid & 15) * 32;
    const int tx = t & 31, ty = t >> 5;
#pragma unroll
    for (int r = 0; r < 32; r += 8)
      Twt[ty + r][tx] = w_rpn[(cob + ty + r) * 4608 + kb + tx];
    __syncthreads();
#pragma unroll
    for (int r = 0; r < 32; r += 8)
      wT[(kb + ty + r) * 512 + cob + tx] = Twt[tx][ty + r];
    return;
  }

  // ---- conv1 part: 16x16 stride16 patchify, split-K over c (z=0..2)
  const int b2 = bid - 2304;
  const int pbase = (b2 & 15) * 64;
  const int cobase = ((b2 >> 4) & 7) * 64;
  const int z = b2 >> 7;
  const int pg = t & 15, cg = t >> 4;
  const int pp0 = pg * 4, cc0 = cg * 4;
  const int py0 = pbase >> 5;
  float acc[4][4] = {};
  for (int kb = 0; kb < 256; kb += 32) {
    const int ky0 = kb >> 4;
#pragma unroll
    for (int l0 = 0; l0 < 2048; l0 += 256) {       // A: 32k x 64p from img
      int l = l0 + t;
      int seg = l >> 9, off = l & 511;
      int py_off = seg >> 1, ky_off = seg & 1;
      int row = (py0 + py_off) * 16 + ky0 + ky_off;
      float v = img[(z * 512 + row) * 512 + off];
      As[ky_off * 16 + (off & 15)][py_off * 32 + (off >> 4)] = v;
    }
#pragma unroll
    for (int it = 0; it < 2; ++it) {               // B: w_bb direct, transposed in LDS
      int idx4 = it * 256 + t;
      int co = idx4 & 63;
      int k4 = (idx4 >> 6) * 4;                    // 0,4,...,28
      float4 v = *(const float4*)&w_bb[(size_t)(cobase + co) * 768 + z * 256 + kb + k4];
      Bs[k4 + 0][co] = v.x;                        // bank=co -> 2-way (free)
      Bs[k4 + 1][co] = v.y;
      Bs[k4 + 2][co] = v.z;
      Bs[k4 + 3][co] = v.w;
    }
    __syncthreads();
#pragma unroll
    for (int kk = 0; kk < 32; ++kk) {
      float4 av = *(const float4*)&As[kk][pp0];
      float4 bv = *(const float4*)&Bs[kk][cc0];
      FMA16();
    }
    __syncthreads();
  }
#pragma unroll
  for (int i = 0; i < 4; ++i) {
    float* o = &featP[((size_t)z * CF + cobase + cc0 + i) * PTOT + pbase + pp0];
    *(float4*)o = make_float4(acc[i][0], acc[i][1], acc[i][2], acc[i][3]);
  }
}

// ---------------- conv2 v3 + fused reduce1: A-stage sums featP z-slices + bias + relu ----------------
__global__ __launch_bounds__(256) void k_conv2(const float* __restrict__ featP,
                                               const float* __restrict__ bias1,
                                               const float* __restrict__ wT,
                                               float* __restrict__ hidP,
                                               int ciPerZ) {
  __shared__ __align__(16) float As[8][6][44];
  __shared__ __align__(16) float Bs[72 * 64];
  const int t = threadIdx.x;
  const int pyb = blockIdx.x * 4;
  const int cob = blockIdx.y * 64;
  const int z = blockIdx.z;
  const int cib = z * ciPerZ;
  const int pg = t & 15, cg = t >> 4;
  const int prow = pg >> 2, px0 = (pg & 3) * 8;
  const int co0 = cg * 4;
  float acc[4][8] = {};
  for (int cc = 0; cc < ciPerZ; cc += 8) {
    {
      int idx4 = t;
#pragma unroll
      for (int it = 0; it < 2; ++it, idx4 += 256) {
        if (idx4 < 480) {
          int ci = idx4 / 60;
          int rem = idx4 - ci * 60;
          int row = rem / 10;
          int col4 = (rem - row * 10) << 2;
          int x = col4 - 4;
          int gy = pyb + row - 1;
          float4 v = make_float4(0.f, 0.f, 0.f, 0.f);
          if (x >= 0 && x < 32 && gy >= 0 && gy < 32) {
            const int c = cib + cc + ci;
            const float* f0 = &featP[(size_t)c * PTOT + gy * 32 + x];
            float4 a0 = *(const float4*)f0;
            float4 a1 = *(const float4*)(f0 + (size_t)CF * PTOT);
            float4 a2 = *(const float4*)(f0 + (size_t)2 * CF * PTOT);
            float b = bias1[c];
            v.x = fmaxf(a0.x + a1.x + a2.x + b, 0.f);
            v.y = fmaxf(a0.y + a1.y + a2.y + b, 0.f);
            v.z = fmaxf(a0.z + a1.z + a2.z + b, 0.f);
            v.w = fmaxf(a0.w + a1.w + a2.w + b, 0.f);
          }
          *(float4*)&As[ci][row][col4] = v;
        }
      }
    }
    {
      const int kg0 = (cib + cc) * 9;
      int idx4 = t;
#pragma unroll
      for (int it = 0; it < 5; ++it, idx4 += 256) {
        if (idx4 < 1152) {
          int k = idx4 >> 4;
          int co4 = (idx4 & 15) << 2;
          *(float4*)&Bs[k * 64 + co4] =
              *(const float4*)&wT[(kg0 + k) * 512 + cob + co4];
        }
      }
    }
    __syncthreads();
#pragma unroll 1
    for (int ci = 0; ci < 8; ++ci) {
#pragma unroll
      for (int dy = 0; dy < 3; ++dy) {
        const float* Ar = &As[ci][prow + dy][px0];
        float rw[16];
        *(float4*)&rw[0]  = *(const float4*)&Ar[0];
        *(float4*)&rw[4]  = *(const float4*)&Ar[4];
        *(float4*)&rw[8]  = *(const float4*)&Ar[8];
        *(float4*)&rw[12] = *(const float4*)&Ar[12];
#pragma unroll
        for (int dx = 0; dx < 3; ++dx) {
          const float* Bp = &Bs[(ci * 9 + dy * 3 + dx) * 64 + co0];
          float4 b0 = *(const float4*)&Bp[0];
          float bm[4] = {b0.x, b0.y, b0.z, b0.w};
#pragma unroll
          for (int m = 0; m < 4; ++m)
#pragma unroll
            for (int j = 0; j < 8; ++j)
              acc[m][j] = fmaf(rw[3 + dx + j], bm[m], acc[m][j]);
        }
      }
    }
    __syncthreads();
  }
  const int prowg = pyb + prow;
#pragma unroll
  for (int m = 0; m < 4; ++m) {
    int co = cob + co0 + m;
    float* o = &hidP[((size_t)z * CF + co) * PTOT + prowg * 32 + px0];
    *(float4*)&o[0] = make_float4(acc[m][0], acc[m][1], acc[m][2], acc[m][3]);
    *(float4*)&o[4] = make_float4(acc[m][4], acc[m][5], acc[m][6], acc[m][7]);
  }
}

// ---------------- reduce2 v2: 32x32 tiles, 512 blocks ----------------
__global__ __launch_bounds__(256) void k_reduce2(const float* __restrict__ hidP,
                                                 const float* __restrict__ bias,
                                                 float* __restrict__ hid_t, int Z) {
  __shared__ float T[32][33];
  const int co0 = blockIdx.x * 32, p0 = blockIdx.y * 32;
  const int t = threadIdx.x;
  {
    int co = t >> 3, p4 = (t & 7) << 2;
    float4 s = make_float4(0.f, 0.f, 0.f, 0.f);
    for (int zz = 0; zz < Z; ++zz) {
      float4 v = *(const float4*)&hidP[((size_t)zz * CF + co0 + co) * PTOT + p0 + p4];
      s.x += v.x; s.y += v.y; s.z += v.z; s.w += v.w;
    }
    float b = bias[co0 + co];
    T[co][p4 + 0] = fmaxf(s.x + b, 0.f);
    T[co][p4 + 1] = fmaxf(s.y + b, 0.f);
    T[co][p4 + 2] = fmaxf(s.z + b, 0.f);
    T[co][p4 + 3] = fmaxf(s.w + b, 0.f);
  }
  __syncthreads();
  {
    int p = t >> 3, co4 = (t & 7) << 2;
    float4 o = make_float4(T[co4][p], T[co4 + 1][p], T[co4 + 2][p], T[co4 + 3][p]);
    *(float4*)&hid_t[(size_t)(p0 + p) * CF + co0 + co4] = o;
  }
}

// ---------------- heads: one wave per pixel; emits score KEYS + deltas ----------------
__global__ __launch_bounds__(256) void k_heads(const float* __restrict__ hid_t,
                                               const float* __restrict__ wcls,
                                               const float* __restrict__ bcls,
                                               const float* __restrict__ wbox,
                                               const float* __restrict__ bbox,
                                               uint32_t* __restrict__ key32,
                                               float* __restrict__ deltas) {
  const int t = threadIdx.x;
  if (blockIdx.x == 256) {
    if (t < 64) key32[NBOX + t] = 0xFFFFFFFFu;
    return;
  }
  const int lane = t & 63, w = t >> 6;
  const int p = blockIdx.x * 4 + w;
  const float* hp = &hid_t[(size_t)p * CF + lane * 8];
  float4 h0 = *(const float4*)hp;
  float4 h1 = *(const float4*)(hp + 4);
#pragma unroll 1
  for (int ch = 0; ch < 45; ++ch) {
    const float* wp = (ch < 9) ? &wcls[(9 + ch) * CF] : &wbox[(ch - 9) * CF];
    float4 w0 = *(const float4*)(wp + lane * 8);
    float4 w1 = *(const float4*)(wp + lane * 8 + 4);
    float s = h0.x * w0.x + h0.y * w0.y + h0.z * w0.z + h0.w * w0.w +
              h1.x * w1.x + h1.y * w1.y + h1.z * w1.z + h1.w * w1.w;
#pragma unroll
    for (int off = 32; off >= 1; off >>= 1) s += __shfl_xor(s, off, 64);
    if (lane == 0) {
      if (ch < 9) key32[p * 9 + ch] = score_key(s + bcls[9 + ch]);
      else        deltas[p * 36 + (ch - 9)] = s + bbox[ch - 9];
    }
  }
}

// ---------------- rank sort stage 1: partial ranks via SGPR-broadcast all-pairs ----------------
__global__ __launch_bounds__(256) void k_rank(const uint32_t* __restrict__ key32,
                                              uint32_t* __restrict__ P) {
  const int t = threadIdx.x;
  const int lane = t & 63, w = t >> 6;
  const int a = blockIdx.x * 4 + w;
  if (a >= 145) return;
  const int by = blockIdx.y;
  const int ig = a * 64 + lane;
  const uint32_t ka = key32[ig];
  uint32_t cnt = 0;
#pragma unroll 1
  for (int w2 = 0; w2 < 8; ++w2) {
    int word = by * 8 + w2;
    if (word >= 145) break;
    const uint32_t* bk = &key32[word * 64];
    const int jbase = word * 64;
#pragma unroll
    for (int s = 0; s < 64; ++s) {
      uint32_t kb = bk[s];                         // uniform -> s_load
      int j = jbase + s;
      cnt += (uint32_t)((kb < ka) || (kb == ka && j < ig));
    }
  }
  P[(size_t)by * NPAD + ig] = cnt;
}

// ---------------- rank sort stage 2: sum partials + decode + scatter ----------------
__global__ __launch_bounds__(256) void k_rfin(const uint32_t* __restrict__ P,
                                              const float* __restrict__ anchors,
                                              const float* __restrict__ deltas,
                                              float4* __restrict__ boxesS) {
  int i = blockIdx.x * 256 + threadIdx.x;
  if (i >= NBOX) return;
  uint32_t rank = 0;
#pragma unroll
  for (int c = 0; c < RCH; ++c) rank += P[(size_t)c * NPAD + i];
  float4 a = ((const float4*)anchors)[i];
  float4 d = ((const float4*)deltas)[i];
  float wa = a.z - a.x, ha = a.w - a.y;
  float cxa = a.x + 0.5f * wa, cya = a.y + 0.5f * ha;
  float dw = fminf(fmaxf(d.z, -4.f), 4.f);
  float dh = fminf(fmaxf(d.w, -4.f), 4.f);
  float cx = cxa + d.x * wa, cy = cya + d.y * ha;
  float ww = wa * expf(dw), hh = ha * expf(dh);
  float x1 = fmaxf(cx - 0.5f * ww, 0.f);
  float y1 = fmaxf(cy - 0.5f * hh, 0.f);
  float x2 = fminf(cx + 0.5f * ww, 511.f);
  float y2 = fminf(cy + 0.5f * hh, 511.f);
  boxesS[rank] = make_float4(x1, y1, x2, y2);
}

// ---------------- IOU bitmask v5: uniform word-pair enumeration, sign-safe compare ----------------
__global__ __launch_bounds__(256) void k_iou(const float4* __restrict__ boxesS,
                                             u64* __restrict__ mask) {
  __shared__ float4 cb[4][64];
  __shared__ float ca[4][64];
  const int t = threadIdx.x;
  const int lane = t & 63, w = t >> 6;
  const int u = blockIdx.x;                        // 0..144
  const int v = blockIdx.y * 4 + w + 1;            // 1..72
  int y = u + v; if (y >= 145) y -= 145;
  const int a_ = min(u, y), b_ = max(u, y);
  const int iw = a_, wj = b_ - 1;                  // iw <= wj in [0,144)

  {
    float4 c = boxesS[wj * 64 + lane];
    cb[w][lane] = c;
    ca[w][lane] = (c.z - c.x) * (c.w - c.y);
  }
  __syncthreads();

  const int i = iw * 64 + lane;
  float4 a = boxesS[i];
  float areaA = (a.z - a.x) * (a.w - a.y);
  u64 bits = 0;
#pragma unroll 4
  for (int jj = 0; jj < 64; ++jj) {
    int j = wj * 64 + jj;
    float4 c = cb[w][jj];
    float iw_ = fmaxf(fminf(a.z, c.z) - fmaxf(a.x, c.x), 0.f);
    float ih_ = fmaxf(fminf(a.w, c.w) - fmaxf(a.y, c.y), 0.f);
    float inter = iw_ * ih_;
    float uni = areaA + ca[w][jj] - inter + 1e-9f;
    float thr = 0.7f * uni;
    bool pos = uni > 0.f;
    bool sup = pos && (inter > thr);
    if (pos && (fabsf(inter - thr) <= thr * 1e-5f))  // rare: exact IEEE path
      sup = (inter / uni) > 0.7f;
    bits |= ((u64)(sup && (j > i))) << jj;
  }
  mask[(size_t)i * NW + wj] = bits;
}

// ---------------- NMS scan v5: sparse shuffle chain, barrier-free main loop ----------------
__global__ __launch_bounds__(64) void k_scan(const u64* __restrict__ mask,
                                             const float4* __restrict__ boxesS,
                                             float* __restrict__ out) {
  __shared__ u64 keepArr[NW];
  __shared__ int pf[NW + 2];
  __shared__ int outIdx[TOPK];
  const int lane = threadIdx.x;

  u64 r0 = 0, r1 = 0, r2 = 0;
  int keptCount = 0;
  int stopSpan = NW - 1;

  u64 dcur = mask[(size_t)lane * NW];              // span-0 diagonal words

  for (int wb = 0; wb < NW; ++wb) {
    u64 v = (wb < 64) ? r0 : ((wb < 128) ? r1 : r2);
    u64 R = __shfl(v, wb & 63, 64);

    u64 dnext = 0;                                 // prefetch next diagonal
    if (wb + 1 < NW)
      dnext = mask[(size_t)((wb + 1) * 64 + lane) * NW + (wb + 1)];

    u64 keepmask = 0;
    u64 notR = ~R;
    while (notR) {                                 // sparse greedy chain
      int rl = __ffsll((long long)notR) - 1;
      keepmask |= 1ull << rl;
      u64 drl = __shfl(dcur, rl, 64);              // row rl's same-span word
      R |= drl;
      u64 above = (rl >= 63) ? 0ull : (~0ull << (rl + 1));
      notR = ~R & above;
    }

    if (keepmask) {                                // OR kept rows, 8 in flight
      u64 km = keepmask;
      while (km) {
        int first = wb * 64 + __ffsll((long long)km) - 1;
        int idx[8];
#pragma unroll
        for (int s = 0; s < 8; ++s) {
          if (km) { idx[s] = wb * 64 + __ffsll((long long)km) - 1; km &= km - 1; }
          else    { idx[s] = first; }
        }
        u64 A[8], B[8], C[8];
#pragma unroll
        for (int s = 0; s < 8; ++s) {
          const u64* q = mask + (size_t)idx[s] * NW;
          A[s] = q[lane];
          B[s] = q[lane + 64];
          C[s] = (lane < 16) ? q[lane + 128] : 0ull;
        }
#pragma unroll
        for (int s = 0; s < 8; ++s) { r0 |= A[s]; r1 |= B[s]; r2 |= C[s]; }
      }
      keptCount += __popcll(keepmask);
    }
    if (lane == 0) keepArr[wb] = keepmask;
    dcur = dnext;
    if (keptCount >= TOPK) { stopSpan = wb; break; }
  }

  __syncthreads();
  if (lane == 0) {
    int acc = 0;
    for (int s = 0; s <= stopSpan; ++s) { pf[s] = acc; acc += __popcll(keepArr[s]); }
    pf[stopSpan + 1] = acc;
  }
  __syncthreads();
  const int keptTotal = pf[stopSpan + 1];

  for (int s = lane; s <= stopSpan; s += 64) {
    u64 km = keepArr[s];
    int slot = pf[s];
    while (km && slot < TOPK) {
      int rl = __ffsll((long long)km) - 1; km &= km - 1;
      outIdx[slot++] = s * 64 + rl;
    }
  }
  if (keptTotal < TOPK) {
    for (int s = lane; s <= stopSpan; s += 64) {
      u64 rm = ~keepArr[s];
      int slot = keptTotal + s * 64 - pf[s];
      while (rm && slot < TOPK) {
        int rl = __ffsll((long long)rm) - 1; rm &= rm - 1;
        outIdx[slot++] = s * 64 + rl;
      }
    }
  }
  __syncthreads();
#pragma unroll
  for (int k0 = 0; k0 < TOPK + 63; k0 += 64) {
    int k = k0 + lane;
    if (k < TOPK) {
      float4 bx = boxesS[outIdx[k]];
      out[k * 4 + 0] = bx.x;
      out[k * 4 + 1] = bx.y;
      out[k * 4 + 2] = bx.z;
      out[k * 4 + 3] = bx.w;
    }
  }
}

extern "C" void kernel_launch(void* const* d_in, const int* in_sizes, int n_in,
                              void* d_out, int out_size, void* d_ws, size_t ws_size,
                              hipStream_t stream) {
  const float* img   = (const float*)d_in[0];
  const float* anch  = (const float*)d_in[1];
  const float* w_bb  = (const float*)d_in[2];
  const float* b_bb  = (const float*)d_in[3];
  const float* w_rpn = (const float*)d_in[4];
  const float* b_rpn = (const float*)d_in[5];
  const float* w_cls = (const float*)d_in[6];
  const float* b_cls = (const float*)d_in[7];
  const float* w_box = (const float*)d_in[8];
  const float* b_box = (const float*)d_in[9];

  char* ws = (char*)d_ws;
  int Z = 16;
  if (ws_size < 22806528ull + 16ull * 2097152ull) Z = 8;
  if (ws_size < 22806528ull + 8ull * 2097152ull)  Z = 4;
  if (ws_size < 22806528ull + 4ull * 2097152ull)  Z = 2;
  if (ws_size < 22806528ull + 2ull * 2097152ull)  Z = 1;

  float* wT    = (float*)(ws);                      // 9 MB
  float* featP = (float*)(ws + 9437184);            // 6 MB
  float* hidP  = (float*)(ws + 15728640);           // Z * 2 MB
  char*  hte   = ws + 15728640 + (size_t)Z * 2097152;
  float* hid_t = (float*)hte;                       // 2 MB
  char*  tail  = hte + 2097152;
  float*    deltas = (float*)(tail);                // 144 KB
  uint32_t* key32  = (uint32_t*)(tail + 0x28000);   // 37 KB
  float4*   boxesS = (float4*)(tail + 0x38000);     // 144 KB
  // Overlays (regions dead by the time they're written):
  uint32_t* P      = (uint32_t*)(ws + 9437184);     // featP region, after conv2
  u64*      mask   = (u64*)(ws);                    // wT+featP region, after rfin
  float*    out    = (float*)d_out;

  hipLaunchKernelGGL(k_front, dim3(2688), dim3(256), 0, stream, w_rpn, w_bb, img, wT, featP);
  hipLaunchKernelGGL(k_conv2, dim3(8, 8, Z), dim3(256), 0, stream, featP, b_bb, wT, hidP, 512 / Z);
  hipLaunchKernelGGL(k_reduce2, dim3(16, 32), dim3(256), 0, stream, hidP, b_rpn, hid_t, Z);
  hipLaunchKernelGGL(k_heads, dim3(257), dim3(256), 0, stream, hid_t, w_cls, b_cls, w_box, b_box, key32, deltas);
  hipLaunchKernelGGL(k_rank, dim3(37, RCH), dim3(256), 0, stream, key32, P);
  hipLaunchKernelGGL(k_rfin, dim3(37), dim3(256), 0, stream, P, anch, deltas, boxesS);
  hipLaunchKernelGGL(k_iou, dim3(145, 18), dim3(256), 0, stream, boxesS, mask);
  hipLaunchKernelGGL(k_scan, dim3(1), dim3(64), 0, stream, mask, boxesS, out);
}